// Round 1
// baseline (68.876 us; speedup 1.0000x reference)
//
#include <hip/hip_runtime.h>

// Problem: B=8, CIN=32, H=W=28, COUT=64, 3x3, pad=1, stride=1. fp32 in/out.
// Folded form:
//   out[b,o,h,w] = sum_{in-bounds taps r} x_r * w2[r][o]  + S2[o] + const[o]
//   w2 = exp(kf+5) - dw;  S2[o] = sum_{all 288 r} w2[r][o]
//   const[o] = 288*dw - dx*colsum[o] + bias[o]
// Single kernel, grid = B*H = 224 x 1024 threads (16 waves, 4/SIMD).
// Wave p owns c in {2p, 2p+1}; w2 in VGPRs (w2r[18]); x rows via wave-uniform
// float4 broadcast loads (7 per row instead of 28 dword loads); cross-wave
// reduction through XOR-swizzled LDS with b128 accesses only.

#define NB 8
#define NC 32
#define NH 28
#define NW 28
#define NO 64

__global__ __launch_bounds__(1024, 1) void fused_conv(
    const float* __restrict__ x,     // [8,32,28,28]
    const float* __restrict__ k,     // [288,64] = [(i*3+j)*32+c][o]
    const float* __restrict__ bias,  // [64]
    const float* __restrict__ dxa,
    const float* __restrict__ dwa,
    float* __restrict__ out)         // [8,64,28,28]
{
    // Rb[p][o][chunk*4+e], chunk XOR-swizzled by (o&7):
    //   write: thread (p,lane=o) stores acc[4c..4c+3] to chunk c^(o&7)
    //   -> b128, 8-lane groups cover all 32 banks, 2 lanes/bank = conflict-free
    __shared__ float Rb[16][NO][32];    // 131072 B
    __shared__ float spart[2][16][NO];  //   8192 B  (ksum / S2 partials)

    const int t    = threadIdx.x;
    const int lane = t & 63;            // = o
    const int p    = t >> 6;            // wave 0..15; owns c in {2p, 2p+1}
    const int b    = blockIdx.x / NH;
    const int h    = blockIdx.x % NH;
    const float dw = dwa[0];
    const float dx = dxa[0];

    // --- w2 into VGPRs (lane-coalesced 256B loads, L2-resident) + partials
    float w2r[18];
    float ksum = 0.0f, s2 = 0.0f;
    const float* kb = k + p * 2 * NO + lane;
    #pragma unroll
    for (int ij = 0; ij < 9; ++ij) {
        #pragma unroll
        for (int cc = 0; cc < 2; ++cc) {
            float kv = kb[(ij * NC + cc) * NO];
            ksum += kv;
            float w2 = __expf(kv + 5.0f) - dw;
            s2 += w2;
            w2r[ij * 2 + cc] = w2;
        }
    }
    spart[0][p][lane] = ksum;
    spart[1][p][lane] = s2;

    // --- main loop: 6 wave-uniform x-rows, boundary taps skipped (contribute 0)
    float acc[NW];
    #pragma unroll
    for (int w = 0; w < NW; ++w) acc[w] = 0.0f;

    #pragma unroll
    for (int i = 0; i < 3; ++i) {
        const int hh = h - 1 + i;
        if (hh >= 0 && hh < NH) {
            #pragma unroll
            for (int cc = 0; cc < 2; ++cc) {
                const int c = p * 2 + cc;
                const int rowoff =
                    __builtin_amdgcn_readfirstlane(((b * NC + c) * NH + hh) * NW);
                // rows are 112 B = 7 x float4, always 16B-aligned
                const float4* xr4 = reinterpret_cast<const float4*>(x + rowoff);
                float4 e4[7];
                #pragma unroll
                for (int m = 0; m < 7; ++m) e4[m] = xr4[m];
                float e[NW];
                #pragma unroll
                for (int m = 0; m < 7; ++m) {
                    e[4 * m + 0] = e4[m].x;
                    e[4 * m + 1] = e4[m].y;
                    e[4 * m + 2] = e4[m].z;
                    e[4 * m + 3] = e4[m].w;
                }

                const float w20 = w2r[(i * 3 + 0) * 2 + cc];
                #pragma unroll
                for (int w = 1; w < NW; ++w) acc[w] = fmaf(e[w - 1], w20, acc[w]);
                const float w21 = w2r[(i * 3 + 1) * 2 + cc];
                #pragma unroll
                for (int w = 0; w < NW; ++w) acc[w] = fmaf(e[w], w21, acc[w]);
                const float w22 = w2r[(i * 3 + 2) * 2 + cc];
                #pragma unroll
                for (int w = 0; w < NW - 1; ++w) acc[w] = fmaf(e[w + 1], w22, acc[w]);
            }
        }
    }

    // --- cross-wave reduction: swizzled b128 writes (conflict-free)
    {
        const int sw = lane & 7;
        float4* rowp = reinterpret_cast<float4*>(&Rb[p][lane][0]);  // 8 chunks
        #pragma unroll
        for (int ch = 0; ch < 7; ++ch) {
            rowp[ch ^ sw] =
                make_float4(acc[4 * ch + 0], acc[4 * ch + 1],
                            acc[4 * ch + 2], acc[4 * ch + 3]);
        }
    }
    __syncthreads();

    if (p < 7) {                        // wave p reduces w-chunk q = p (w = 4p..4p+3)
        const int o  = lane;
        const int q  = p;
        const int sw = o & 7;
        float4 s = make_float4(0.0f, 0.0f, 0.0f, 0.0f);
        #pragma unroll
        for (int pp = 0; pp < 16; ++pp) {
            float4 v = reinterpret_cast<float4*>(&Rb[pp][o][0])[q ^ sw];
            s.x += v.x; s.y += v.y; s.z += v.z; s.w += v.w;
        }
        float cs = 0.0f, ss = 0.0f;
        #pragma unroll
        for (int pp = 0; pp < 16; ++pp) {
            cs += spart[0][pp][o];
            ss += spart[1][pp][o];
        }
        const float cst = 288.0f * dw - dx * cs + bias[o] + ss;
        const long obase = ((long)(b * NO + o) * NH + h) * NW + q * 4;
        // (obase*4) % 16 == 0: row stride 112 B, +16 B per chunk -> aligned
        float4 r = make_float4(s.x + cst, s.y + cst, s.z + cst, s.w + cst);
        *reinterpret_cast<float4*>(out + obase) = r;
    }
}

extern "C" void kernel_launch(void* const* d_in, const int* in_sizes, int n_in,
                              void* d_out, int out_size, void* d_ws, size_t ws_size,
                              hipStream_t stream) {
    const float* x    = (const float*)d_in[0];
    const float* k    = (const float*)d_in[1];
    const float* bias = (const float*)d_in[2];
    const float* dxa  = (const float*)d_in[3];
    const float* dwa  = (const float*)d_in[4];
    float* out        = (float*)d_out;

    fused_conv<<<NB * NH, 1024, 0, stream>>>(x, k, bias, dxa, dwa, out);
}